// Round 3
// baseline (290.033 us; speedup 1.0000x reference)
//
#include <hip/hip_runtime.h>

// B=4, T=2048, DIM=1024, H=16, Dh=64. fp32 in/out, bf16 internal.
// ws layout (bytes):
//   xn     @ 0          : 8192x1024 bf16  (16 MB)
//   wqkvT  @ 16777216   : 3072x1024 bf16  ( 6 MB)
//   woutT  @ 23068672   : 1024x1024 bf16  ( 2 MB)
//   qkv    @ 25165824   : q,k: [b][h][t][d]; v: [b][h][d][t] bf16 (48 MB)
//          q pre-scaled by 0.125*log2(e)  (softmax runs in exp2 domain)
//   attno  @ 75497472   : 8192x1024 bf16  (16 MB)   [b*T+t][h*64+d]

#define DIMX 1024
#define TSEQ 2048
#define NB 4
#define NH 16
#define DH 64
#define NROWS (NB * TSEQ)
#define QSCALE 0.18033688011112042f /* 0.125 * log2(e) */

typedef __bf16 bf16_t;
typedef __bf16 bf16x8 __attribute__((ext_vector_type(8)));
typedef __bf16 bf16x4 __attribute__((ext_vector_type(4)));
typedef float f32x4 __attribute__((ext_vector_type(4)));

#if __has_builtin(__builtin_amdgcn_exp2f)
#define EXP2F __builtin_amdgcn_exp2f
#else
#define EXP2F exp2f
#endif

__device__ __forceinline__ bf16x4 cvt4(f32x4 v) {
    return __builtin_convertvector(v, bf16x4);  // fptrunc RNE -> v_cvt_pk_bf16_f32
}
__device__ __forceinline__ void async16(const bf16_t* g, bf16_t* l) {
    __builtin_amdgcn_global_load_lds(
        (const __attribute__((address_space(1))) unsigned int*)g,
        (__attribute__((address_space(3))) unsigned int*)l, 16, 0, 0);
}

// ---------------- LayerNorm: fp32 in -> bf16 out ----------------
__global__ __launch_bounds__(256) void ln_kernel(
    const float* __restrict__ x, const float* __restrict__ g,
    const float* __restrict__ b, bf16_t* __restrict__ xn) {
    int row = blockIdx.x, tid = threadIdx.x;
    const float4 xv = *(const float4*)(x + (size_t)row * DIMX + tid * 4);
    float s = xv.x + xv.y + xv.z + xv.w;
    float q = xv.x * xv.x + xv.y * xv.y + xv.z * xv.z + xv.w * xv.w;
    for (int o = 32; o > 0; o >>= 1) {
        s += __shfl_xor(s, o);
        q += __shfl_xor(q, o);
    }
    __shared__ float2 red[4];
    int wave = tid >> 6, lane = tid & 63;
    if (lane == 0) red[wave] = make_float2(s, q);
    __syncthreads();
    float2 r0 = red[0], r1 = red[1], r2 = red[2], r3 = red[3];
    s = r0.x + r1.x + r2.x + r3.x;
    q = r0.y + r1.y + r2.y + r3.y;
    float mu = s * (1.0f / DIMX);
    float var = q * (1.0f / DIMX) - mu * mu;
    float rstd = rsqrtf(var + 1e-5f);
    float4 gv = *(const float4*)(g + tid * 4);
    float4 bv = *(const float4*)(b + tid * 4);
    f32x4 r;
    r[0] = (xv.x - mu) * rstd * gv.x + bv.x;
    r[1] = (xv.y - mu) * rstd * gv.y + bv.y;
    r[2] = (xv.z - mu) * rstd * gv.z + bv.z;
    r[3] = (xv.w - mu) * rstd * gv.w + bv.w;
    *(bf16x4*)(xn + (size_t)row * DIMX + tid * 4) = cvt4(r);
}

// ---------------- Transpose + cast fp32 [R x C] -> bf16 [C x R] ----------------
__global__ __launch_bounds__(256) void transpose_cast(
    const float* __restrict__ src, bf16_t* __restrict__ dst, int R, int C) {
    __shared__ float tile[32][33];
    int c0 = blockIdx.x * 32, r0 = blockIdx.y * 32;
    int tx = threadIdx.x, ty = threadIdx.y;  // block (32,8)
    for (int i = ty; i < 32; i += 8)
        tile[i][tx] = src[(size_t)(r0 + i) * C + c0 + tx];
    __syncthreads();
    for (int i = ty; i < 32; i += 8)
        dst[(size_t)(c0 + i) * R + r0 + tx] = (bf16_t)tile[tx][i];
}

// ---------------- 256x256 / BK=64 / 8-wave phased MFMA GEMM ----------------
// (unchanged from round 1; see comments there)
#define MFMA16 __builtin_amdgcn_mfma_f32_16x16x32_bf16

template <int MODE>
__global__ __launch_bounds__(512, 2) void gemm256(
    const bf16_t* __restrict__ A, const bf16_t* __restrict__ BT,
    void* __restrict__ Cout, const float* __restrict__ bias, int M, int N, int K) {
    __shared__ __align__(16) bf16_t As[2][256 * 64];
    __shared__ __align__(16) bf16_t Bs[2][256 * 64];
    int tid = threadIdx.x, lane = tid & 63, wave = tid >> 6;
    int lm = lane & 15, quad = lane >> 4;
    int wr = wave >> 2, wc = wave & 3;

    int nbx = gridDim.x;
    int nwg = nbx * gridDim.y;
    int linear = blockIdx.y * nbx + blockIdx.x;
    int cpx = nwg >> 3;
    int swz = (linear & 7) * cpx + (linear >> 3);
    int bx = swz % nbx, by = swz / nbx;
    int m0 = by * 256, n0 = bx * 256;

    int srow = tid >> 3, sc8 = tid & 7;
    int scol = (sc8 ^ (srow & 7)) << 3;
    const bf16_t* ga = A + (size_t)(m0 + srow) * K + scol;
    const bf16_t* gb = BT + (size_t)(n0 + srow) * K + scol;
    int ldst = tid << 3;

    int sw0 = ((quad ^ (lm & 7)) << 3);
    int sw1 = (((4 + quad) ^ (lm & 7)) << 3);

    f32x4 zero = {0.f, 0.f, 0.f, 0.f};
    f32x4 acc[8][4];
#pragma unroll
    for (int i = 0; i < 8; ++i)
#pragma unroll
        for (int j = 0; j < 4; ++j) acc[i][j] = zero;

#pragma unroll
    for (int i = 0; i < 4; ++i) async16(ga + (size_t)i * 64 * K, &As[0][i * 4096 + ldst]);
#pragma unroll
    for (int i = 0; i < 4; ++i) async16(gb + (size_t)i * 64 * K, &Bs[0][i * 4096 + ldst]);
    asm volatile("s_waitcnt vmcnt(0)" ::: "memory");
    __builtin_amdgcn_s_barrier();

    int nkt = K >> 6;
    for (int kt = 0; kt < nkt; ++kt) {
        int c = kt & 1;
        int k1 = (kt + 1) << 6;
        bool pf = (kt + 1) < nkt;
        const bf16_t* pa = &As[c][0];
        const bf16_t* pb = &Bs[c][0];
        bf16_t* na = &As[c ^ 1][0];
        bf16_t* nb = &Bs[c ^ 1][0];
        bf16x8 af[4][2], bfr[2][2];

        // ---- phase 0 ----
#pragma unroll
        for (int t = 0; t < 4; ++t) {
            int ro = (wr * 128 + t * 16 + lm) * 64;
            af[t][0] = *(const bf16x8*)&pa[ro + sw0];
            af[t][1] = *(const bf16x8*)&pa[ro + sw1];
        }
#pragma unroll
        for (int t = 0; t < 2; ++t) {
            int ro = (wc * 64 + t * 16 + lm) * 64;
            bfr[t][0] = *(const bf16x8*)&pb[ro + sw0];
            bfr[t][1] = *(const bf16x8*)&pb[ro + sw1];
        }
        if (pf) {
#pragma unroll
            for (int i = 0; i < 4; ++i)
                async16(ga + (size_t)i * 64 * K + k1, &na[i * 4096 + ldst]);
        }
        __builtin_amdgcn_s_barrier();
        asm volatile("s_waitcnt lgkmcnt(0)" ::: "memory");
        __builtin_amdgcn_s_setprio(1);
#pragma unroll
        for (int mt = 0; mt < 4; ++mt)
#pragma unroll
            for (int nt = 0; nt < 2; ++nt) {
                acc[mt][nt] = MFMA16(af[mt][0], bfr[nt][0], acc[mt][nt], 0, 0, 0);
                acc[mt][nt] = MFMA16(af[mt][1], bfr[nt][1], acc[mt][nt], 0, 0, 0);
            }
        __builtin_amdgcn_s_setprio(0);
        __builtin_amdgcn_s_barrier();

        // ---- phase 1 ----
#pragma unroll
        for (int t = 0; t < 2; ++t) {
            int ro = (wc * 64 + (2 + t) * 16 + lm) * 64;
            bfr[t][0] = *(const bf16x8*)&pb[ro + sw0];
            bfr[t][1] = *(const bf16x8*)&pb[ro + sw1];
        }
        if (pf) {
#pragma unroll
            for (int i = 0; i < 4; ++i)
                async16(gb + (size_t)i * 64 * K + k1, &nb[i * 4096 + ldst]);
        }
        __builtin_amdgcn_s_barrier();
        asm volatile("s_waitcnt lgkmcnt(0)" ::: "memory");
        __builtin_amdgcn_s_setprio(1);
#pragma unroll
        for (int mt = 0; mt < 4; ++mt)
#pragma unroll
            for (int nt = 0; nt < 2; ++nt) {
                acc[mt][2 + nt] = MFMA16(af[mt][0], bfr[nt][0], acc[mt][2 + nt], 0, 0, 0);
                acc[mt][2 + nt] = MFMA16(af[mt][1], bfr[nt][1], acc[mt][2 + nt], 0, 0, 0);
            }
        __builtin_amdgcn_s_setprio(0);
        __builtin_amdgcn_s_barrier();

        // ---- phase 2 ----
#pragma unroll
        for (int t = 0; t < 4; ++t) {
            int ro = (wr * 128 + (4 + t) * 16 + lm) * 64;
            af[t][0] = *(const bf16x8*)&pa[ro + sw0];
            af[t][1] = *(const bf16x8*)&pa[ro + sw1];
        }
        __builtin_amdgcn_s_barrier();
        asm volatile("s_waitcnt lgkmcnt(0)" ::: "memory");
        __builtin_amdgcn_s_setprio(1);
#pragma unroll
        for (int mt = 0; mt < 4; ++mt)
#pragma unroll
            for (int nt = 0; nt < 2; ++nt) {
                acc[4 + mt][2 + nt] = MFMA16(af[mt][0], bfr[nt][0], acc[4 + mt][2 + nt], 0, 0, 0);
                acc[4 + mt][2 + nt] = MFMA16(af[mt][1], bfr[nt][1], acc[4 + mt][2 + nt], 0, 0, 0);
            }
        __builtin_amdgcn_s_setprio(0);
        __builtin_amdgcn_s_barrier();

        // ---- phase 3 ----
#pragma unroll
        for (int t = 0; t < 2; ++t) {
            int ro = (wc * 64 + t * 16 + lm) * 64;
            bfr[t][0] = *(const bf16x8*)&pb[ro + sw0];
            bfr[t][1] = *(const bf16x8*)&pb[ro + sw1];
        }
        __builtin_amdgcn_s_barrier();
        asm volatile("s_waitcnt lgkmcnt(0)" ::: "memory");
        __builtin_amdgcn_s_setprio(1);
#pragma unroll
        for (int mt = 0; mt < 4; ++mt)
#pragma unroll
            for (int nt = 0; nt < 2; ++nt) {
                acc[4 + mt][nt] = MFMA16(af[mt][0], bfr[nt][0], acc[4 + mt][nt], 0, 0, 0);
                acc[4 + mt][nt] = MFMA16(af[mt][1], bfr[nt][1], acc[4 + mt][nt], 0, 0, 0);
            }
        __builtin_amdgcn_s_setprio(0);
        asm volatile("s_waitcnt vmcnt(0)" ::: "memory");
        __builtin_amdgcn_s_barrier();
    }

    // ---------------- epilogue ----------------
#pragma unroll
    for (int mt = 0; mt < 8; ++mt) {
#pragma unroll
        for (int nt = 0; nt < 4; ++nt) {
            int m = m0 + wr * 128 + mt * 16 + quad * 4;  // +r
            int n = n0 + wc * 64 + nt * 16 + lm;
            if (MODE == 1) {
                int sel = n >> 10, nn = n & 1023, h = nn >> 6, d = nn & 63;
                int b = m >> 11, t = m & 2047;
                if (sel == 2) {
                    *(bf16x4*)((bf16_t*)Cout + (size_t)2 * 8388608 +
                               ((size_t)((b * NH + h) * DH + d)) * TSEQ + t) = cvt4(acc[mt][nt]);
                } else {
                    f32x4 sv = acc[mt][nt] * (sel == 0 ? QSCALE : 1.0f);
                    bf16x4 c4 = cvt4(sv);
#pragma unroll
                    for (int r = 0; r < 4; ++r)
                        ((bf16_t*)Cout)[(size_t)sel * 8388608 +
                                        ((size_t)((b * NH + h) * TSEQ + t + r)) * DH + d] = c4[r];
                }
            } else {
                float bn = bias[n];
#pragma unroll
                for (int r = 0; r < 4; ++r)
                    ((float*)Cout)[(size_t)(m + r) * N + n] = acc[mt][nt][r] + bn;
            }
        }
    }
}

// ---------------- MFMA flash attention, 8 waves x 32 q-rows ----------------
// grid (T/256, B*H); block 512 = 8 waves; wave handles 32 q rows (2 x 16).
// 512 blocks x 8 waves = 16 waves/CU = 4 waves/SIMD: wave-phase diversity so
// MFMA-phase waves overlap softmax-phase waves (same K/V HBM traffic as the
// 4-wave variant since block count is unchanged). K/V double-buffered in LDS;
// setprio(1) around MFMA clusters (T5). Softmax: S^T = K Q^T, C-init=-16,
// exp2 domain, no running max; P round-trips per-wave 2KB LDS (FIFO-safe).
__global__ __launch_bounds__(512, 4) void attn_mfma(
    const bf16_t* __restrict__ qkv, bf16_t* __restrict__ o) {
    int bh = blockIdx.y;
    int qt = blockIdx.x;  // 256-row q tile
    const bf16_t* qb = qkv + (size_t)bh * TSEQ * DH;
    const bf16_t* kb = qkv + (size_t)8388608 + (size_t)bh * TSEQ * DH;
    const bf16_t* vb = qkv + (size_t)16777216 + (size_t)bh * DH * TSEQ;  // [d][t]
    int tid = threadIdx.x, wave = tid >> 6, lane = tid & 63;
    int lm = lane & 15, quad = lane >> 4, lx = lm & 7;

    __shared__ __align__(16) bf16_t Ks[2][64 * 64];
    __shared__ __align__(16) bf16_t Vt[2][64 * 64];
    __shared__ __align__(16) bf16_t Ps[8 * 1024];  // per-wave 16x64, reused per u

    // staging: 512 threads cover 64 rows x 8 granules; source col swizzled
    int roff = tid >> 3;
    int cperm = ((tid & 7) ^ (roff & 7)) * 8;
    const bf16_t* kp = kb + (size_t)roff * DH + cperm;
    const bf16_t* vp = vb + (size_t)roff * TSEQ + cperm;
    int l0 = tid * 8;  // linear LDS dest granule

    // Q B-frags [u][ks]: B[n=i][k=d], i = qt*256 + wave*32 + u*16 + lm
    bf16x8 qf[2][2];
#pragma unroll
    for (int u = 0; u < 2; ++u)
#pragma unroll
        for (int ks = 0; ks < 2; ++ks)
            qf[u][ks] = *(const bf16x8*)(qb +
                (size_t)(qt * 256 + wave * 32 + u * 16 + lm) * DH + ks * 32 + quad * 8);

    f32x4 zero = {0.f, 0.f, 0.f, 0.f};
    f32x4 m16 = {-16.f, -16.f, -16.f, -16.f};
    f32x4 acc[2][4];  // [u][dt]
#pragma unroll
    for (int u = 0; u < 2; ++u)
#pragma unroll
        for (int dt = 0; dt < 4; ++dt) acc[u][dt] = zero;
    f32x4 l4[2] = {zero, zero};

    int fo0 = (quad ^ lx) * 8;        // ks=0 fragment granule (swizzled)
    int fo1 = ((4 + quad) ^ lx) * 8;  // ks=1
    int pb = wave * 1024 + lm * 64;

    // prologue: stage tile 0 into buffer 0
    async16(kp, &Ks[0][l0]);
    async16(vp, &Vt[0][l0]);
    kp += 64 * DH; vp += 64;
    asm volatile("s_waitcnt vmcnt(0)" ::: "memory");
    __builtin_amdgcn_s_barrier();

    for (int jt = 0; jt < TSEQ / 64; ++jt) {
        int c = jt & 1;
        // issue next tile into spare buffer (WAR-safe: barrier ended prev iter)
        if (jt + 1 < TSEQ / 64) {
            async16(kp, &Ks[c ^ 1][l0]);
            async16(vp, &Vt[c ^ 1][l0]);
            kp += 64 * DH; vp += 64;
        }

        // K A-frags once per jt, shared across the 2 q-subtiles
        bf16x8 kf[4][2];
#pragma unroll
        for (int nt = 0; nt < 4; ++nt) {
            kf[nt][0] = *(const bf16x8*)&Ks[c][(nt * 16 + lm) * 64 + fo0];
            kf[nt][1] = *(const bf16x8*)&Ks[c][(nt * 16 + lm) * 64 + fo1];
        }

        bf16x8 pf[2][2];
#pragma unroll
        for (int u = 0; u < 2; ++u) {
            // S^T: lane holds S^T[j=nt*16+quad*4+r][i=lm]; C-init=-16 = shift
            f32x4 s[4];
            __builtin_amdgcn_s_setprio(1);
#pragma unroll
            for (int nt = 0; nt < 4; ++nt) {
                s[nt] = __builtin_amdgcn_mfma_f32_16x16x32_bf16(kf[nt][0], qf[u][0], m16, 0, 0, 0);
                s[nt] = __builtin_amdgcn_mfma_f32_16x16x32_bf16(kf[nt][1], qf[u][1], s[nt], 0, 0, 0);
            }
            __builtin_amdgcn_s_setprio(0);
            // p = exp2(s); accumulate l; pack P to per-wave LDS (A-layout, swizzled)
#pragma unroll
            for (int nt = 0; nt < 4; ++nt) {
                f32x4 p;
#pragma unroll
                for (int e = 0; e < 4; ++e) p[e] = EXP2F(s[nt][e]);
                l4[u] += p;
                *(bf16x4*)&Ps[pb + ((nt * 2 + (quad >> 1)) ^ lx) * 8 + (quad & 1) * 4] = cvt4(p);
            }
            // read back as A-frags; same-wave FIFO order -> no barrier, safe reuse
            pf[u][0] = *(const bf16x8*)&Ps[pb + fo0];
            pf[u][1] = *(const bf16x8*)&Ps[pb + fo1];
        }

        // O^T += Vt P^T : V frags read once per dt, shared across u
        __builtin_amdgcn_s_setprio(1);
#pragma unroll
        for (int dt = 0; dt < 4; ++dt) {
            bf16x8 vf0 = *(const bf16x8*)&Vt[c][(dt * 16 + lm) * 64 + fo0];
            bf16x8 vf1 = *(const bf16x8*)&Vt[c][(dt * 16 + lm) * 64 + fo1];
#pragma unroll
            for (int u = 0; u < 2; ++u) {
                acc[u][dt] = __builtin_amdgcn_mfma_f32_16x16x32_bf16(vf0, pf[u][0], acc[u][dt], 0, 0, 0);
                acc[u][dt] = __builtin_amdgcn_mfma_f32_16x16x32_bf16(vf1, pf[u][1], acc[u][dt], 0, 0, 0);
            }
        }
        __builtin_amdgcn_s_setprio(0);

        // next tile's loads (a full compute phase old) + all waves done reading c
        asm volatile("s_waitcnt vmcnt(0)" ::: "memory");
        __builtin_amdgcn_s_barrier();
    }

    int b = bh >> 4, h = bh & 15;
#pragma unroll
    for (int u = 0; u < 2; ++u) {
        float l = (l4[u][0] + l4[u][1]) + (l4[u][2] + l4[u][3]);
        l += __shfl_xor(l, 16);
        l += __shfl_xor(l, 32);
        float rl = 1.0f / l;
        int t = qt * 256 + wave * 32 + u * 16 + lm;
#pragma unroll
        for (int dt = 0; dt < 4; ++dt) {
            f32x4 ov = acc[u][dt] * rl;
            *(bf16x4*)(o + ((size_t)(b * TSEQ + t)) * DIMX + h * DH + dt * 16 + quad * 4) = cvt4(ov);
        }
    }
}

extern "C" void kernel_launch(void* const* d_in, const int* in_sizes, int n_in,
                              void* d_out, int out_size, void* d_ws, size_t ws_size,
                              hipStream_t stream) {
    const float* x = (const float*)d_in[0];
    const float* g = (const float*)d_in[1];
    const float* be = (const float*)d_in[2];
    const float* w_qkv = (const float*)d_in[3];
    const float* w_out = (const float*)d_in[4];
    const float* b_out = (const float*)d_in[5];
    float* out = (float*)d_out;
    char* ws = (char*)d_ws;

    bf16_t* xn = (bf16_t*)(ws);
    bf16_t* wqkvT = (bf16_t*)(ws + 16777216);
    bf16_t* woutT = (bf16_t*)(ws + 23068672);
    bf16_t* qkv = (bf16_t*)(ws + 25165824);
    bf16_t* attno = (bf16_t*)(ws + 75497472);

    ln_kernel<<<NROWS, 256, 0, stream>>>(x, g, be, xn);
    transpose_cast<<<dim3(96, 32), dim3(32, 8), 0, stream>>>(w_qkv, wqkvT, 1024, 3072);
    transpose_cast<<<dim3(32, 32), dim3(32, 8), 0, stream>>>(w_out, woutT, 1024, 1024);
    gemm256<1><<<dim3(12, 32), 512, 0, stream>>>(xn, wqkvT, (void*)qkv, nullptr, NROWS, 3072, 1024);
    attn_mfma<<<dim3(8, 64), 512, 0, stream>>>(qkv, attno);
    gemm256<2><<<dim3(4, 32), 512, 0, stream>>>(attno, woutT, (void*)out, b_out, NROWS, 1024, 1024);
}

// Round 4
// 285.223 us; speedup vs baseline: 1.0169x; 1.0169x over previous
//
#include <hip/hip_runtime.h>

// B=4, T=2048, DIM=1024, H=16, Dh=64. fp32 in/out, bf16 internal.
// ws layout (bytes):
//   xn     @ 0          : 8192x1024 bf16  (16 MB)
//   wqkvT  @ 16777216   : 3072x1024 bf16  ( 6 MB)
//   woutT  @ 23068672   : 1024x1024 bf16  ( 2 MB)
//   qkv    @ 25165824   : q,k: [b][h][t][d]; v: [b][h][d][t] bf16 (48 MB)
//          q pre-scaled by 0.125*log2(e)  (softmax runs in exp2 domain)
//   attno  @ 75497472   : 8192x1024 bf16  (16 MB)   [b*T+t][h*64+d]

#define DIMX 1024
#define TSEQ 2048
#define NB 4
#define NH 16
#define DH 64
#define NROWS (NB * TSEQ)
#define QSCALE 0.18033688011112042f /* 0.125 * log2(e) */

typedef __bf16 bf16_t;
typedef __bf16 bf16x8 __attribute__((ext_vector_type(8)));
typedef __bf16 bf16x4 __attribute__((ext_vector_type(4)));
typedef float f32x4 __attribute__((ext_vector_type(4)));

#if __has_builtin(__builtin_amdgcn_exp2f)
#define EXP2F __builtin_amdgcn_exp2f
#else
#define EXP2F exp2f
#endif

__device__ __forceinline__ bf16x4 cvt4(f32x4 v) {
    return __builtin_convertvector(v, bf16x4);  // fptrunc RNE -> v_cvt_pk_bf16_f32
}
__device__ __forceinline__ void async16(const bf16_t* g, bf16_t* l) {
    __builtin_amdgcn_global_load_lds(
        (const __attribute__((address_space(1))) unsigned int*)g,
        (__attribute__((address_space(3))) unsigned int*)l, 16, 0, 0);
}

// ---------------- LayerNorm: fp32 in -> bf16 out ----------------
__global__ __launch_bounds__(256) void ln_kernel(
    const float* __restrict__ x, const float* __restrict__ g,
    const float* __restrict__ b, bf16_t* __restrict__ xn) {
    int row = blockIdx.x, tid = threadIdx.x;
    const float4 xv = *(const float4*)(x + (size_t)row * DIMX + tid * 4);
    float s = xv.x + xv.y + xv.z + xv.w;
    float q = xv.x * xv.x + xv.y * xv.y + xv.z * xv.z + xv.w * xv.w;
    for (int o = 32; o > 0; o >>= 1) {
        s += __shfl_xor(s, o);
        q += __shfl_xor(q, o);
    }
    __shared__ float2 red[4];
    int wave = tid >> 6, lane = tid & 63;
    if (lane == 0) red[wave] = make_float2(s, q);
    __syncthreads();
    float2 r0 = red[0], r1 = red[1], r2 = red[2], r3 = red[3];
    s = r0.x + r1.x + r2.x + r3.x;
    q = r0.y + r1.y + r2.y + r3.y;
    float mu = s * (1.0f / DIMX);
    float var = q * (1.0f / DIMX) - mu * mu;
    float rstd = rsqrtf(var + 1e-5f);
    float4 gv = *(const float4*)(g + tid * 4);
    float4 bv = *(const float4*)(b + tid * 4);
    f32x4 r;
    r[0] = (xv.x - mu) * rstd * gv.x + bv.x;
    r[1] = (xv.y - mu) * rstd * gv.y + bv.y;
    r[2] = (xv.z - mu) * rstd * gv.z + bv.z;
    r[3] = (xv.w - mu) * rstd * gv.w + bv.w;
    *(bf16x4*)(xn + (size_t)row * DIMX + tid * 4) = cvt4(r);
}

// ---------------- Transpose + cast fp32 [R x C] -> bf16 [C x R] ----------------
__global__ __launch_bounds__(256) void transpose_cast(
    const float* __restrict__ src, bf16_t* __restrict__ dst, int R, int C) {
    __shared__ float tile[32][33];
    int c0 = blockIdx.x * 32, r0 = blockIdx.y * 32;
    int tx = threadIdx.x, ty = threadIdx.y;  // block (32,8)
    for (int i = ty; i < 32; i += 8)
        tile[i][tx] = src[(size_t)(r0 + i) * C + c0 + tx];
    __syncthreads();
    for (int i = ty; i < 32; i += 8)
        dst[(size_t)(c0 + i) * R + r0 + tx] = (bf16_t)tile[tx][i];
}

// ---------------- 256x256 / BK=64 / 8-wave phased MFMA GEMM ----------------
// (unchanged from round 1; see comments there)
#define MFMA16 __builtin_amdgcn_mfma_f32_16x16x32_bf16

template <int MODE>
__global__ __launch_bounds__(512, 2) void gemm256(
    const bf16_t* __restrict__ A, const bf16_t* __restrict__ BT,
    void* __restrict__ Cout, const float* __restrict__ bias, int M, int N, int K) {
    __shared__ __align__(16) bf16_t As[2][256 * 64];
    __shared__ __align__(16) bf16_t Bs[2][256 * 64];
    int tid = threadIdx.x, lane = tid & 63, wave = tid >> 6;
    int lm = lane & 15, quad = lane >> 4;
    int wr = wave >> 2, wc = wave & 3;

    int nbx = gridDim.x;
    int nwg = nbx * gridDim.y;
    int linear = blockIdx.y * nbx + blockIdx.x;
    int cpx = nwg >> 3;
    int swz = (linear & 7) * cpx + (linear >> 3);
    int bx = swz % nbx, by = swz / nbx;
    int m0 = by * 256, n0 = bx * 256;

    int srow = tid >> 3, sc8 = tid & 7;
    int scol = (sc8 ^ (srow & 7)) << 3;
    const bf16_t* ga = A + (size_t)(m0 + srow) * K + scol;
    const bf16_t* gb = BT + (size_t)(n0 + srow) * K + scol;
    int ldst = tid << 3;

    int sw0 = ((quad ^ (lm & 7)) << 3);
    int sw1 = (((4 + quad) ^ (lm & 7)) << 3);

    f32x4 zero = {0.f, 0.f, 0.f, 0.f};
    f32x4 acc[8][4];
#pragma unroll
    for (int i = 0; i < 8; ++i)
#pragma unroll
        for (int j = 0; j < 4; ++j) acc[i][j] = zero;

#pragma unroll
    for (int i = 0; i < 4; ++i) async16(ga + (size_t)i * 64 * K, &As[0][i * 4096 + ldst]);
#pragma unroll
    for (int i = 0; i < 4; ++i) async16(gb + (size_t)i * 64 * K, &Bs[0][i * 4096 + ldst]);
    asm volatile("s_waitcnt vmcnt(0)" ::: "memory");
    __builtin_amdgcn_s_barrier();

    int nkt = K >> 6;
    for (int kt = 0; kt < nkt; ++kt) {
        int c = kt & 1;
        int k1 = (kt + 1) << 6;
        bool pf = (kt + 1) < nkt;
        const bf16_t* pa = &As[c][0];
        const bf16_t* pb = &Bs[c][0];
        bf16_t* na = &As[c ^ 1][0];
        bf16_t* nb = &Bs[c ^ 1][0];
        bf16x8 af[4][2], bfr[2][2];

        // ---- phase 0 ----
#pragma unroll
        for (int t = 0; t < 4; ++t) {
            int ro = (wr * 128 + t * 16 + lm) * 64;
            af[t][0] = *(const bf16x8*)&pa[ro + sw0];
            af[t][1] = *(const bf16x8*)&pa[ro + sw1];
        }
#pragma unroll
        for (int t = 0; t < 2; ++t) {
            int ro = (wc * 64 + t * 16 + lm) * 64;
            bfr[t][0] = *(const bf16x8*)&pb[ro + sw0];
            bfr[t][1] = *(const bf16x8*)&pb[ro + sw1];
        }
        if (pf) {
#pragma unroll
            for (int i = 0; i < 4; ++i)
                async16(ga + (size_t)i * 64 * K + k1, &na[i * 4096 + ldst]);
        }
        __builtin_amdgcn_s_barrier();
        asm volatile("s_waitcnt lgkmcnt(0)" ::: "memory");
        __builtin_amdgcn_s_setprio(1);
#pragma unroll
        for (int mt = 0; mt < 4; ++mt)
#pragma unroll
            for (int nt = 0; nt < 2; ++nt) {
                acc[mt][nt] = MFMA16(af[mt][0], bfr[nt][0], acc[mt][nt], 0, 0, 0);
                acc[mt][nt] = MFMA16(af[mt][1], bfr[nt][1], acc[mt][nt], 0, 0, 0);
            }
        __builtin_amdgcn_s_setprio(0);
        __builtin_amdgcn_s_barrier();

        // ---- phase 1 ----
#pragma unroll
        for (int t = 0; t < 2; ++t) {
            int ro = (wc * 64 + (2 + t) * 16 + lm) * 64;
            bfr[t][0] = *(const bf16x8*)&pb[ro + sw0];
            bfr[t][1] = *(const bf16x8*)&pb[ro + sw1];
        }
        if (pf) {
#pragma unroll
            for (int i = 0; i < 4; ++i)
                async16(gb + (size_t)i * 64 * K + k1, &nb[i * 4096 + ldst]);
        }
        __builtin_amdgcn_s_barrier();
        asm volatile("s_waitcnt lgkmcnt(0)" ::: "memory");
        __builtin_amdgcn_s_setprio(1);
#pragma unroll
        for (int mt = 0; mt < 4; ++mt)
#pragma unroll
            for (int nt = 0; nt < 2; ++nt) {
                acc[mt][2 + nt] = MFMA16(af[mt][0], bfr[nt][0], acc[mt][2 + nt], 0, 0, 0);
                acc[mt][2 + nt] = MFMA16(af[mt][1], bfr[nt][1], acc[mt][2 + nt], 0, 0, 0);
            }
        __builtin_amdgcn_s_setprio(0);
        __builtin_amdgcn_s_barrier();

        // ---- phase 2 ----
#pragma unroll
        for (int t = 0; t < 4; ++t) {
            int ro = (wr * 128 + (4 + t) * 16 + lm) * 64;
            af[t][0] = *(const bf16x8*)&pa[ro + sw0];
            af[t][1] = *(const bf16x8*)&pa[ro + sw1];
        }
        __builtin_amdgcn_s_barrier();
        asm volatile("s_waitcnt lgkmcnt(0)" ::: "memory");
        __builtin_amdgcn_s_setprio(1);
#pragma unroll
        for (int mt = 0; mt < 4; ++mt)
#pragma unroll
            for (int nt = 0; nt < 2; ++nt) {
                acc[4 + mt][2 + nt] = MFMA16(af[mt][0], bfr[nt][0], acc[4 + mt][2 + nt], 0, 0, 0);
                acc[4 + mt][2 + nt] = MFMA16(af[mt][1], bfr[nt][1], acc[4 + mt][2 + nt], 0, 0, 0);
            }
        __builtin_amdgcn_s_setprio(0);
        __builtin_amdgcn_s_barrier();

        // ---- phase 3 ----
#pragma unroll
        for (int t = 0; t < 2; ++t) {
            int ro = (wc * 64 + t * 16 + lm) * 64;
            bfr[t][0] = *(const bf16x8*)&pb[ro + sw0];
            bfr[t][1] = *(const bf16x8*)&pb[ro + sw1];
        }
        __builtin_amdgcn_s_barrier();
        asm volatile("s_waitcnt lgkmcnt(0)" ::: "memory");
        __builtin_amdgcn_s_setprio(1);
#pragma unroll
        for (int mt = 0; mt < 4; ++mt)
#pragma unroll
            for (int nt = 0; nt < 2; ++nt) {
                acc[4 + mt][nt] = MFMA16(af[mt][0], bfr[nt][0], acc[4 + mt][nt], 0, 0, 0);
                acc[4 + mt][nt] = MFMA16(af[mt][1], bfr[nt][1], acc[4 + mt][nt], 0, 0, 0);
            }
        __builtin_amdgcn_s_setprio(0);
        asm volatile("s_waitcnt vmcnt(0)" ::: "memory");
        __builtin_amdgcn_s_barrier();
    }

    // ---------------- epilogue ----------------
#pragma unroll
    for (int mt = 0; mt < 8; ++mt) {
#pragma unroll
        for (int nt = 0; nt < 4; ++nt) {
            int m = m0 + wr * 128 + mt * 16 + quad * 4;  // +r
            int n = n0 + wc * 64 + nt * 16 + lm;
            if (MODE == 1) {
                int sel = n >> 10, nn = n & 1023, h = nn >> 6, d = nn & 63;
                int b = m >> 11, t = m & 2047;
                if (sel == 2) {
                    *(bf16x4*)((bf16_t*)Cout + (size_t)2 * 8388608 +
                               ((size_t)((b * NH + h) * DH + d)) * TSEQ + t) = cvt4(acc[mt][nt]);
                } else {
                    f32x4 sv = acc[mt][nt] * (sel == 0 ? QSCALE : 1.0f);
                    bf16x4 c4 = cvt4(sv);
#pragma unroll
                    for (int r = 0; r < 4; ++r)
                        ((bf16_t*)Cout)[(size_t)sel * 8388608 +
                                        ((size_t)((b * NH + h) * TSEQ + t + r)) * DH + d] = c4[r];
                }
            } else {
                float bn = bias[n];
#pragma unroll
                for (int r = 0; r < 4; ++r)
                    ((float*)Cout)[(size_t)(m + r) * N + n] = acc[mt][nt][r] + bn;
            }
        }
    }
}

// ---------------- MFMA flash attention, 8 waves x 32 q-rows ----------------
// grid (T/256, B*H); block 512 = 8 waves; wave handles 32 q rows (2 x 16).
// S^T = K Q^T in exp2 domain, C-init=-16, no running max. NO P LDS round-trip:
// K rows are PERMUTED into the QK^T A-tiles (krow(nt,lm)) so that each lane's
// 16 S-values are exactly the two PV B-frag granules that lane needs; P is
// packed to bf16 in registers. MFMA contracts k positionally, so the ks=1
// V-frag reads column granule (4|(quad^2)) to carry the same j at the same
// position. LDS store swizzle f(row)=(row&3)|((row&8)>>1) applied on the
// global source (linear LDS dest); kf reads then swizzle by lm&7, vf by f.
// All LDS accesses conflict-free by construction; K/V double-buffered.
__global__ __launch_bounds__(512, 4) void attn_mfma(
    const bf16_t* __restrict__ qkv, bf16_t* __restrict__ o) {
    int bh = blockIdx.y;
    int qt = blockIdx.x;  // 256-row q tile
    const bf16_t* qb = qkv + (size_t)bh * TSEQ * DH;
    const bf16_t* kb = qkv + (size_t)8388608 + (size_t)bh * TSEQ * DH;
    const bf16_t* vb = qkv + (size_t)16777216 + (size_t)bh * DH * TSEQ;  // [d][t]
    int tid = threadIdx.x, wave = tid >> 6, lane = tid & 63;
    int lm = lane & 15, quad = lane >> 4, lx = lm & 7;

    __shared__ __align__(16) bf16_t Ks[2][64 * 64];
    __shared__ __align__(16) bf16_t Vt[2][64 * 64];

    // staging: thread covers row roff, LDS granule tid&7; source granule
    // (tid&7)^f(roff) with f(r) = (r&3)|((r&8)>>1)
    int roff = tid >> 3;
    int fr = (roff & 3) | ((roff & 8) >> 1);
    int cperm = ((tid & 7) ^ fr) * 8;
    const bf16_t* kp = kb + (size_t)roff * DH + cperm;
    const bf16_t* vp = vb + (size_t)roff * TSEQ + cperm;
    int l0 = tid * 8;  // linear LDS dest granule

    // Q B-frags [u][ks]: B[n=i][k=d], i = qt*256 + wave*32 + u*16 + lm
    bf16x8 qf[2][2];
#pragma unroll
    for (int u = 0; u < 2; ++u)
#pragma unroll
        for (int ks = 0; ks < 2; ++ks)
            qf[u][ks] = *(const bf16x8*)(qb +
                (size_t)(qt * 256 + wave * 32 + u * 16 + lm) * DH + ks * 32 + quad * 8);

    f32x4 zero = {0.f, 0.f, 0.f, 0.f};
    f32x4 m16 = {-16.f, -16.f, -16.f, -16.f};
    f32x4 acc[2][4];  // [u][dt]
#pragma unroll
    for (int u = 0; u < 2; ++u)
#pragma unroll
        for (int dt = 0; dt < 4; ++dt) acc[u][dt] = zero;
    f32x4 l4[2] = {zero, zero};

    // K-row permutation: nt-tile row m=lm holds K row krow(nt,lm) so that the
    // QK^T output lands, per lane, exactly in PV B-frag order.
    int qh = lm >> 2, rr = lm & 3;
    int krow0 = 8 * qh + rr;              // nt=0: j = 8*quad + e
    int krow1 = krow0 + 4;                // nt=1: j = 8*quad + 4 + e
    int krow2 = 32 + 8 * (qh ^ 2) + rr;   // nt=2: j = 32 + 8*(quad^2) + e
    int krow3 = krow2 + 4;                // nt=3: j = 36 + 8*(quad^2) + e
    // f(krow(nt,lm)) == lm&7 for all nt -> kf column offsets swizzle by lx:
    int fo0 = (quad ^ lx) * 8;        // ks=0 granule
    int fo1 = ((4 + quad) ^ lx) * 8;  // ks=1 granule
    // V-frag column offsets: logical granule quad (ks=0) / 4|(quad^2) (ks=1),
    // swizzled by fv = f(row) of the rows vf reads (dt*16+lm -> depends on lm only)
    int fv = (lm & 3) | ((lm & 8) >> 1);
    int vo0 = (quad ^ fv) * 8;
    int vo1 = ((4 | (quad ^ 2)) ^ fv) * 8;

    // prologue: stage tile 0 into buffer 0
    async16(kp, &Ks[0][l0]);
    async16(vp, &Vt[0][l0]);
    kp += 64 * DH; vp += 64;
    asm volatile("s_waitcnt vmcnt(0)" ::: "memory");
    __builtin_amdgcn_s_barrier();

    for (int jt = 0; jt < TSEQ / 64; ++jt) {
        int c = jt & 1;
        // issue next tile into spare buffer (WAR-safe: barrier ended prev iter)
        if (jt + 1 < TSEQ / 64) {
            async16(kp, &Ks[c ^ 1][l0]);
            async16(vp, &Vt[c ^ 1][l0]);
            kp += 64 * DH; vp += 64;
        }

        // K A-frags once per jt (permuted rows), shared across the 2 q-subtiles
        bf16x8 kf[4][2];
        kf[0][0] = *(const bf16x8*)&Ks[c][krow0 * 64 + fo0];
        kf[0][1] = *(const bf16x8*)&Ks[c][krow0 * 64 + fo1];
        kf[1][0] = *(const bf16x8*)&Ks[c][krow1 * 64 + fo0];
        kf[1][1] = *(const bf16x8*)&Ks[c][krow1 * 64 + fo1];
        kf[2][0] = *(const bf16x8*)&Ks[c][krow2 * 64 + fo0];
        kf[2][1] = *(const bf16x8*)&Ks[c][krow2 * 64 + fo1];
        kf[3][0] = *(const bf16x8*)&Ks[c][krow3 * 64 + fo0];
        kf[3][1] = *(const bf16x8*)&Ks[c][krow3 * 64 + fo1];

        bf16x8 pf[2][2];
#pragma unroll
        for (int u = 0; u < 2; ++u) {
            // S^T with permuted j-labels; C-init=-16 = softmax shift
            f32x4 s[4];
            __builtin_amdgcn_s_setprio(1);
#pragma unroll
            for (int nt = 0; nt < 4; ++nt) {
                s[nt] = __builtin_amdgcn_mfma_f32_16x16x32_bf16(kf[nt][0], qf[u][0], m16, 0, 0, 0);
                s[nt] = __builtin_amdgcn_mfma_f32_16x16x32_bf16(kf[nt][1], qf[u][1], s[nt], 0, 0, 0);
            }
            __builtin_amdgcn_s_setprio(0);
            // p = exp2(s); accumulate l; pack P into PV B-frags IN REGISTERS
            f32x4 p[4];
#pragma unroll
            for (int nt = 0; nt < 4; ++nt) {
#pragma unroll
                for (int e = 0; e < 4; ++e) p[nt][e] = EXP2F(s[nt][e]);
                l4[u] += p[nt];
            }
            bf16x4 c0 = cvt4(p[0]), c1 = cvt4(p[1]), c2 = cvt4(p[2]), c3 = cvt4(p[3]);
            pf[u][0] = __builtin_shufflevector(c0, c1, 0, 1, 2, 3, 4, 5, 6, 7);
            pf[u][1] = __builtin_shufflevector(c2, c3, 0, 1, 2, 3, 4, 5, 6, 7);
        }

        // O^T += Vt P^T : V frags read once per dt, shared across u.
        // ks=1 V columns use granule 4|(quad^2) to match pf[1]'s j-positions.
        __builtin_amdgcn_s_setprio(1);
#pragma unroll
        for (int dt = 0; dt < 4; ++dt) {
            bf16x8 vf0 = *(const bf16x8*)&Vt[c][(dt * 16 + lm) * 64 + vo0];
            bf16x8 vf1 = *(const bf16x8*)&Vt[c][(dt * 16 + lm) * 64 + vo1];
#pragma unroll
            for (int u = 0; u < 2; ++u) {
                acc[u][dt] = __builtin_amdgcn_mfma_f32_16x16x32_bf16(vf0, pf[u][0], acc[u][dt], 0, 0, 0);
                acc[u][dt] = __builtin_amdgcn_mfma_f32_16x16x32_bf16(vf1, pf[u][1], acc[u][dt], 0, 0, 0);
            }
        }
        __builtin_amdgcn_s_setprio(0);

        // next tile's loads (a full compute phase old) + all waves done reading c
        asm volatile("s_waitcnt vmcnt(0)" ::: "memory");
        __builtin_amdgcn_s_barrier();
    }

    int b = bh >> 4, h = bh & 15;
#pragma unroll
    for (int u = 0; u < 2; ++u) {
        float l = (l4[u][0] + l4[u][1]) + (l4[u][2] + l4[u][3]);
        l += __shfl_xor(l, 16);
        l += __shfl_xor(l, 32);
        float rl = 1.0f / l;
        int t = qt * 256 + wave * 32 + u * 16 + lm;
#pragma unroll
        for (int dt = 0; dt < 4; ++dt) {
            f32x4 ov = acc[u][dt] * rl;
            *(bf16x4*)(o + ((size_t)(b * TSEQ + t)) * DIMX + h * DH + dt * 16 + quad * 4) = cvt4(ov);
        }
    }
}

extern "C" void kernel_launch(void* const* d_in, const int* in_sizes, int n_in,
                              void* d_out, int out_size, void* d_ws, size_t ws_size,
                              hipStream_t stream) {
    const float* x = (const float*)d_in[0];
    const float* g = (const float*)d_in[1];
    const float* be = (const float*)d_in[2];
    const float* w_qkv = (const float*)d_in[3];
    const float* w_out = (const float*)d_in[4];
    const float* b_out = (const float*)d_in[5];
    float* out = (float*)d_out;
    char* ws = (char*)d_ws;

    bf16_t* xn = (bf16_t*)(ws);
    bf16_t* wqkvT = (bf16_t*)(ws + 16777216);
    bf16_t* woutT = (bf16_t*)(ws + 23068672);
    bf16_t* qkv = (bf16_t*)(ws + 25165824);
    bf16_t* attno = (bf16_t*)(ws + 75497472);

    ln_kernel<<<NROWS, 256, 0, stream>>>(x, g, be, xn);
    transpose_cast<<<dim3(96, 32), dim3(32, 8), 0, stream>>>(w_qkv, wqkvT, 1024, 3072);
    transpose_cast<<<dim3(32, 32), dim3(32, 8), 0, stream>>>(w_out, woutT, 1024, 1024);
    gemm256<1><<<dim3(12, 32), 512, 0, stream>>>(xn, wqkvT, (void*)qkv, nullptr, NROWS, 3072, 1024);
    attn_mfma<<<dim3(8, 64), 512, 0, stream>>>(qkv, attno);
    gemm256<2><<<dim3(4, 32), 512, 0, stream>>>(attno, woutT, (void*)out, b_out, NROWS, 1024, 1024);
}

// Round 5
// 256.801 us; speedup vs baseline: 1.1294x; 1.1107x over previous
//
#include <hip/hip_runtime.h>

// B=4, T=2048, DIM=1024, H=16, Dh=64. fp32 in/out, bf16 internal.
// ws layout (bytes):
//   xn     @ 0          : 8192x1024 bf16  (16 MB)
//   wqkvT  @ 16777216   : 3072x1024 bf16  ( 6 MB)
//   woutT  @ 23068672   : 1024x1024 bf16  ( 2 MB)
//   qkv    @ 25165824   : q,k: [b][h][t][d]; v: [b][h][d][t] bf16 (48 MB)
//          q pre-scaled by 0.125*log2(e)  (softmax runs in exp2 domain)
//   attno  @ 75497472   : 8192x1024 bf16  (16 MB)   [b*T+t][h*64+d]

#define DIMX 1024
#define TSEQ 2048
#define NB 4
#define NH 16
#define DH 64
#define NROWS (NB * TSEQ)
#define QSCALE 0.18033688011112042f /* 0.125 * log2(e) */

typedef __bf16 bf16_t;
typedef __bf16 bf16x8 __attribute__((ext_vector_type(8)));
typedef __bf16 bf16x4 __attribute__((ext_vector_type(4)));
typedef float f32x4 __attribute__((ext_vector_type(4)));

#if __has_builtin(__builtin_amdgcn_exp2f)
#define EXP2F __builtin_amdgcn_exp2f
#else
#define EXP2F exp2f
#endif

__device__ __forceinline__ bf16x4 cvt4(f32x4 v) {
    return __builtin_convertvector(v, bf16x4);  // fptrunc RNE -> v_cvt_pk_bf16_f32
}
__device__ __forceinline__ void async16(const bf16_t* g, bf16_t* l) {
    __builtin_amdgcn_global_load_lds(
        (const __attribute__((address_space(1))) unsigned int*)g,
        (__attribute__((address_space(3))) unsigned int*)l, 16, 0, 0);
}

// ---------------- LayerNorm: fp32 in -> bf16 out ----------------
__global__ __launch_bounds__(256) void ln_kernel(
    const float* __restrict__ x, const float* __restrict__ g,
    const float* __restrict__ b, bf16_t* __restrict__ xn) {
    int row = blockIdx.x, tid = threadIdx.x;
    const float4 xv = *(const float4*)(x + (size_t)row * DIMX + tid * 4);
    float s = xv.x + xv.y + xv.z + xv.w;
    float q = xv.x * xv.x + xv.y * xv.y + xv.z * xv.z + xv.w * xv.w;
    for (int o = 32; o > 0; o >>= 1) {
        s += __shfl_xor(s, o);
        q += __shfl_xor(q, o);
    }
    __shared__ float2 red[4];
    int wave = tid >> 6, lane = tid & 63;
    if (lane == 0) red[wave] = make_float2(s, q);
    __syncthreads();
    float2 r0 = red[0], r1 = red[1], r2 = red[2], r3 = red[3];
    s = r0.x + r1.x + r2.x + r3.x;
    q = r0.y + r1.y + r2.y + r3.y;
    float mu = s * (1.0f / DIMX);
    float var = q * (1.0f / DIMX) - mu * mu;
    float rstd = rsqrtf(var + 1e-5f);
    float4 gv = *(const float4*)(g + tid * 4);
    float4 bv = *(const float4*)(b + tid * 4);
    f32x4 r;
    r[0] = (xv.x - mu) * rstd * gv.x + bv.x;
    r[1] = (xv.y - mu) * rstd * gv.y + bv.y;
    r[2] = (xv.z - mu) * rstd * gv.z + bv.z;
    r[3] = (xv.w - mu) * rstd * gv.w + bv.w;
    *(bf16x4*)(xn + (size_t)row * DIMX + tid * 4) = cvt4(r);
}

// ---------------- Transpose + cast fp32 [R x C] -> bf16 [C x R] ----------------
__global__ __launch_bounds__(256) void transpose_cast(
    const float* __restrict__ src, bf16_t* __restrict__ dst, int R, int C) {
    __shared__ float tile[32][33];
    int c0 = blockIdx.x * 32, r0 = blockIdx.y * 32;
    int tx = threadIdx.x, ty = threadIdx.y;  // block (32,8)
    for (int i = ty; i < 32; i += 8)
        tile[i][tx] = src[(size_t)(r0 + i) * C + c0 + tx];
    __syncthreads();
    for (int i = ty; i < 32; i += 8)
        dst[(size_t)(c0 + i) * R + r0 + tx] = (bf16_t)tile[tx][i];
}

// ---------------- 128x128 / BK=64 / 4-wave phased MFMA GEMM ----------------
// C[m][n] = sum_k A[m][k]*BT[n][k]   (A row-major [M][K], BT row-major [N][K])
// 256 threads = 4 waves (2M x 2N), per-wave 64x64 output, acc[4][4].
// LDS 64 KiB (dbuf A[128][64] + B[128][64] bf16) -> 2 independent blocks/CU:
// their phase drift hides each other's barrier/drain stalls (m97/m114
// implicit overlap). Staging via global_load_lds(16B), bank-conflict swizzle
// on the GLOBAL source granule (c8 ^= row&7) + same XOR on ds_read (rule 21).
// 2 phases per K-tile; all 8 next-tile stages issued at P0 (both dest buffers
// free since the previous boundary barrier); single vmcnt(0) at tile boundary.
// Grids are even: gemm1 24x64=1536 (3 full rounds), gemm2 8x64=512 (1 round).
// MODE 1: scatter to qkv (q,k -> [b][h][t][d]; v -> [b][h][d][t]; q*QSCALE)
// MODE 2: fp32 out row-major + bias
#define MFMA16 __builtin_amdgcn_mfma_f32_16x16x32_bf16

template <int MODE>
__global__ __launch_bounds__(256, 2) void gemm128p(
    const bf16_t* __restrict__ A, const bf16_t* __restrict__ BT,
    void* __restrict__ Cout, const float* __restrict__ bias, int M, int N, int K) {
    __shared__ __align__(16) bf16_t As[2][128 * 64];
    __shared__ __align__(16) bf16_t Bs[2][128 * 64];
    int tid = threadIdx.x, lane = tid & 63, wave = tid >> 6;
    int lm = lane & 15, quad = lane >> 4;
    int wr = wave >> 1, wc = wave & 1;

    // bijective XCD swizzle (nwg % 8 == 0 for both call sites)
    int nbx = gridDim.x;
    int nwg = nbx * gridDim.y;
    int linear = blockIdx.y * nbx + blockIdx.x;
    int cpx = nwg >> 3;
    int swz = (linear & 7) * cpx + (linear >> 3);
    int bx = swz % nbx, by = swz / nbx;
    int m0 = by * 128, n0 = bx * 128;

    // staging: issue i covers rows i*32 + (tid>>3), granule tid&7; source col
    // swizzled by row&7 (= (tid>>3)&7, invariant in i). Linear LDS dest.
    int srow = tid >> 3, sc8 = tid & 7;
    int scol = (sc8 ^ (srow & 7)) << 3;
    const bf16_t* ga = A + (size_t)(m0 + srow) * K + scol;
    const bf16_t* gb = BT + (size_t)(n0 + srow) * K + scol;
    int ldst = tid << 3;  // element offset of issue-0 granule (linear dest)

    // swizzled fragment-read column offsets (elements), granule = ks*4+quad
    int sw0 = ((quad ^ (lm & 7)) << 3);
    int sw1 = (((4 + quad) ^ (lm & 7)) << 3);

    f32x4 zero = {0.f, 0.f, 0.f, 0.f};
    f32x4 acc[4][4];
#pragma unroll
    for (int i = 0; i < 4; ++i)
#pragma unroll
        for (int j = 0; j < 4; ++j) acc[i][j] = zero;

    // prologue: stage K-tile 0 into buffer 0
#pragma unroll
    for (int i = 0; i < 4; ++i) async16(ga + (size_t)(i * 32) * K, &As[0][i * 2048 + ldst]);
#pragma unroll
    for (int i = 0; i < 4; ++i) async16(gb + (size_t)(i * 32) * K, &Bs[0][i * 2048 + ldst]);
    asm volatile("s_waitcnt vmcnt(0)" ::: "memory");
    __builtin_amdgcn_s_barrier();

    int nkt = K >> 6;
    for (int kt = 0; kt < nkt; ++kt) {
        int c = kt & 1;
        int k1 = (kt + 1) << 6;
        bool pf = (kt + 1) < nkt;
        const bf16_t* pa = &As[c][0];
        const bf16_t* pb = &Bs[c][0];
        bf16_t* na = &As[c ^ 1][0];
        bf16_t* nb = &Bs[c ^ 1][0];
        bf16x8 af[4][2], bfr[2][2];

        // ---- phase 0: read A(mt0-3) + B(nt0-1); issue ALL next-tile stages ----
#pragma unroll
        for (int t = 0; t < 4; ++t) {
            int ro = (wr * 64 + t * 16 + lm) * 64;
            af[t][0] = *(const bf16x8*)&pa[ro + sw0];
            af[t][1] = *(const bf16x8*)&pa[ro + sw1];
        }
#pragma unroll
        for (int t = 0; t < 2; ++t) {
            int ro = (wc * 64 + t * 16 + lm) * 64;
            bfr[t][0] = *(const bf16x8*)&pb[ro + sw0];
            bfr[t][1] = *(const bf16x8*)&pb[ro + sw1];
        }
        if (pf) {
#pragma unroll
            for (int i = 0; i < 4; ++i)
                async16(ga + (size_t)(i * 32) * K + k1, &na[i * 2048 + ldst]);
#pragma unroll
            for (int i = 0; i < 4; ++i)
                async16(gb + (size_t)(i * 32) * K + k1, &nb[i * 2048 + ldst]);
        }
        __builtin_amdgcn_s_barrier();
        asm volatile("s_waitcnt lgkmcnt(0)" ::: "memory");
        __builtin_amdgcn_s_setprio(1);
#pragma unroll
        for (int mt = 0; mt < 4; ++mt)
#pragma unroll
            for (int nt = 0; nt < 2; ++nt) {
                acc[mt][nt] = MFMA16(af[mt][0], bfr[nt][0], acc[mt][nt], 0, 0, 0);
                acc[mt][nt] = MFMA16(af[mt][1], bfr[nt][1], acc[mt][nt], 0, 0, 0);
            }
        __builtin_amdgcn_s_setprio(0);
        __builtin_amdgcn_s_barrier();

        // ---- phase 1: read B(nt2-3), reuse A(mt0-3); tile boundary ----
#pragma unroll
        for (int t = 0; t < 2; ++t) {
            int ro = (wc * 64 + (2 + t) * 16 + lm) * 64;
            bfr[t][0] = *(const bf16x8*)&pb[ro + sw0];
            bfr[t][1] = *(const bf16x8*)&pb[ro + sw1];
        }
        __builtin_amdgcn_s_barrier();
        asm volatile("s_waitcnt lgkmcnt(0)" ::: "memory");
        __builtin_amdgcn_s_setprio(1);
#pragma unroll
        for (int mt = 0; mt < 4; ++mt)
#pragma unroll
            for (int nt = 0; nt < 2; ++nt) {
                acc[mt][2 + nt] = MFMA16(af[mt][0], bfr[nt][0], acc[mt][2 + nt], 0, 0, 0);
                acc[mt][2 + nt] = MFMA16(af[mt][1], bfr[nt][1], acc[mt][2 + nt], 0, 0, 0);
            }
        __builtin_amdgcn_s_setprio(0);
        // next-tile stages (issued at P0, a full tile of compute old)
        asm volatile("s_waitcnt vmcnt(0)" ::: "memory");
        __builtin_amdgcn_s_barrier();
    }

    // ---------------- epilogue ----------------
#pragma unroll
    for (int mt = 0; mt < 4; ++mt) {
#pragma unroll
        for (int nt = 0; nt < 4; ++nt) {
            int m = m0 + wr * 64 + mt * 16 + quad * 4;  // +r
            int n = n0 + wc * 64 + nt * 16 + lm;
            if (MODE == 1) {
                int sel = n >> 10, nn = n & 1023, h = nn >> 6, d = nn & 63;
                int b = m >> 11, t = m & 2047;
                if (sel == 2) {
                    *(bf16x4*)((bf16_t*)Cout + (size_t)2 * 8388608 +
                               ((size_t)((b * NH + h) * DH + d)) * TSEQ + t) = cvt4(acc[mt][nt]);
                } else {
                    f32x4 sv = acc[mt][nt] * (sel == 0 ? QSCALE : 1.0f);
                    bf16x4 c4 = cvt4(sv);
#pragma unroll
                    for (int r = 0; r < 4; ++r)
                        ((bf16_t*)Cout)[(size_t)sel * 8388608 +
                                        ((size_t)((b * NH + h) * TSEQ + t + r)) * DH + d] = c4[r];
                }
            } else {
                float bn = bias[n];
#pragma unroll
                for (int r = 0; r < 4; ++r)
                    ((float*)Cout)[(size_t)(m + r) * N + n] = acc[mt][nt][r] + bn;
            }
        }
    }
}

// ---------------- MFMA flash attention, 8 waves x 32 q-rows ----------------
// (unchanged from round 3: register-resident P via K-row permutation)
__global__ __launch_bounds__(512, 4) void attn_mfma(
    const bf16_t* __restrict__ qkv, bf16_t* __restrict__ o) {
    int bh = blockIdx.y;
    int qt = blockIdx.x;  // 256-row q tile
    const bf16_t* qb = qkv + (size_t)bh * TSEQ * DH;
    const bf16_t* kb = qkv + (size_t)8388608 + (size_t)bh * TSEQ * DH;
    const bf16_t* vb = qkv + (size_t)16777216 + (size_t)bh * DH * TSEQ;  // [d][t]
    int tid = threadIdx.x, wave = tid >> 6, lane = tid & 63;
    int lm = lane & 15, quad = lane >> 4, lx = lm & 7;

    __shared__ __align__(16) bf16_t Ks[2][64 * 64];
    __shared__ __align__(16) bf16_t Vt[2][64 * 64];

    int roff = tid >> 3;
    int fr = (roff & 3) | ((roff & 8) >> 1);
    int cperm = ((tid & 7) ^ fr) * 8;
    const bf16_t* kp = kb + (size_t)roff * DH + cperm;
    const bf16_t* vp = vb + (size_t)roff * TSEQ + cperm;
    int l0 = tid * 8;  // linear LDS dest granule

    bf16x8 qf[2][2];
#pragma unroll
    for (int u = 0; u < 2; ++u)
#pragma unroll
        for (int ks = 0; ks < 2; ++ks)
            qf[u][ks] = *(const bf16x8*)(qb +
                (size_t)(qt * 256 + wave * 32 + u * 16 + lm) * DH + ks * 32 + quad * 8);

    f32x4 zero = {0.f, 0.f, 0.f, 0.f};
    f32x4 m16 = {-16.f, -16.f, -16.f, -16.f};
    f32x4 acc[2][4];  // [u][dt]
#pragma unroll
    for (int u = 0; u < 2; ++u)
#pragma unroll
        for (int dt = 0; dt < 4; ++dt) acc[u][dt] = zero;
    f32x4 l4[2] = {zero, zero};

    int qh = lm >> 2, rr = lm & 3;
    int krow0 = 8 * qh + rr;
    int krow1 = krow0 + 4;
    int krow2 = 32 + 8 * (qh ^ 2) + rr;
    int krow3 = krow2 + 4;
    int fo0 = (quad ^ lx) * 8;
    int fo1 = ((4 + quad) ^ lx) * 8;
    int fv = (lm & 3) | ((lm & 8) >> 1);
    int vo0 = (quad ^ fv) * 8;
    int vo1 = ((4 | (quad ^ 2)) ^ fv) * 8;

    async16(kp, &Ks[0][l0]);
    async16(vp, &Vt[0][l0]);
    kp += 64 * DH; vp += 64;
    asm volatile("s_waitcnt vmcnt(0)" ::: "memory");
    __builtin_amdgcn_s_barrier();

    for (int jt = 0; jt < TSEQ / 64; ++jt) {
        int c = jt & 1;
        if (jt + 1 < TSEQ / 64) {
            async16(kp, &Ks[c ^ 1][l0]);
            async16(vp, &Vt[c ^ 1][l0]);
            kp += 64 * DH; vp += 64;
        }

        bf16x8 kf[4][2];
        kf[0][0] = *(const bf16x8*)&Ks[c][krow0 * 64 + fo0];
        kf[0][1] = *(const bf16x8*)&Ks[c][krow0 * 64 + fo1];
        kf[1][0] = *(const bf16x8*)&Ks[c][krow1 * 64 + fo0];
        kf[1][1] = *(const bf16x8*)&Ks[c][krow1 * 64 + fo1];
        kf[2][0] = *(const bf16x8*)&Ks[c][krow2 * 64 + fo0];
        kf[2][1] = *(const bf16x8*)&Ks[c][krow2 * 64 + fo1];
        kf[3][0] = *(const bf16x8*)&Ks[c][krow3 * 64 + fo0];
        kf[3][1] = *(const bf16x8*)&Ks[c][krow3 * 64 + fo1];

        bf16x8 pf[2][2];
#pragma unroll
        for (int u = 0; u < 2; ++u) {
            f32x4 s[4];
            __builtin_amdgcn_s_setprio(1);
#pragma unroll
            for (int nt = 0; nt < 4; ++nt) {
                s[nt] = __builtin_amdgcn_mfma_f32_16x16x32_bf16(kf[nt][0], qf[u][0], m16, 0, 0, 0);
                s[nt] = __builtin_amdgcn_mfma_f32_16x16x32_bf16(kf[nt][1], qf[u][1], s[nt], 0, 0, 0);
            }
            __builtin_amdgcn_s_setprio(0);
            f32x4 p[4];
#pragma unroll
            for (int nt = 0; nt < 4; ++nt) {
#pragma unroll
                for (int e = 0; e < 4; ++e) p[nt][e] = EXP2F(s[nt][e]);
                l4[u] += p[nt];
            }
            bf16x4 c0 = cvt4(p[0]), c1 = cvt4(p[1]), c2 = cvt4(p[2]), c3 = cvt4(p[3]);
            pf[u][0] = __builtin_shufflevector(c0, c1, 0, 1, 2, 3, 4, 5, 6, 7);
            pf[u][1] = __builtin_shufflevector(c2, c3, 0, 1, 2, 3, 4, 5, 6, 7);
        }

        __builtin_amdgcn_s_setprio(1);
#pragma unroll
        for (int dt = 0; dt < 4; ++dt) {
            bf16x8 vf0 = *(const bf16x8*)&Vt[c][(dt * 16 + lm) * 64 + vo0];
            bf16x8 vf1 = *(const bf16x8*)&Vt[c][(dt * 16 + lm) * 64 + vo1];
#pragma unroll
            for (int u = 0; u < 2; ++u) {
                acc[u][dt] = __builtin_amdgcn_mfma_f32_16x16x32_bf16(vf0, pf[u][0], acc[u][dt], 0, 0, 0);
                acc[u][dt] = __builtin_amdgcn_mfma_f32_16x16x32_bf16(vf1, pf[u][1], acc[u][dt], 0, 0, 0);
            }
        }
        __builtin_amdgcn_s_setprio(0);

        asm volatile("s_waitcnt vmcnt(0)" ::: "memory");
        __builtin_amdgcn_s_barrier();
    }

    int b = bh >> 4, h = bh & 15;
#pragma unroll
    for (int u = 0; u < 2; ++u) {
        float l = (l4[u][0] + l4[u][1]) + (l4[u][2] + l4[u][3]);
        l += __shfl_xor(l, 16);
        l += __shfl_xor(l, 32);
        float rl = 1.0f / l;
        int t = qt * 256 + wave * 32 + u * 16 + lm;
#pragma unroll
        for (int dt = 0; dt < 4; ++dt) {
            f32x4 ov = acc[u][dt] * rl;
            *(bf16x4*)(o + ((size_t)(b * TSEQ + t)) * DIMX + h * DH + dt * 16 + quad * 4) = cvt4(ov);
        }
    }
}

extern "C" void kernel_launch(void* const* d_in, const int* in_sizes, int n_in,
                              void* d_out, int out_size, void* d_ws, size_t ws_size,
                              hipStream_t stream) {
    const float* x = (const float*)d_in[0];
    const float* g = (const float*)d_in[1];
    const float* be = (const float*)d_in[2];
    const float* w_qkv = (const float*)d_in[3];
    const float* w_out = (const float*)d_in[4];
    const float* b_out = (const float*)d_in[5];
    float* out = (float*)d_out;
    char* ws = (char*)d_ws;

    bf16_t* xn = (bf16_t*)(ws);
    bf16_t* wqkvT = (bf16_t*)(ws + 16777216);
    bf16_t* woutT = (bf16_t*)(ws + 23068672);
    bf16_t* qkv = (bf16_t*)(ws + 25165824);
    bf16_t* attno = (bf16_t*)(ws + 75497472);

    ln_kernel<<<NROWS, 256, 0, stream>>>(x, g, be, xn);
    transpose_cast<<<dim3(96, 32), dim3(32, 8), 0, stream>>>(w_qkv, wqkvT, 1024, 3072);
    transpose_cast<<<dim3(32, 32), dim3(32, 8), 0, stream>>>(w_out, woutT, 1024, 1024);
    gemm128p<1><<<dim3(24, 64), 256, 0, stream>>>(xn, wqkvT, (void*)qkv, nullptr, NROWS, 3072, 1024);
    attn_mfma<<<dim3(8, 64), 512, 0, stream>>>(qkv, attno);
    gemm128p<2><<<dim3(8, 64), 256, 0, stream>>>(attno, woutT, (void*)out, b_out, NROWS, 1024, 1024);
}